// Round 1
// baseline (973.564 us; speedup 1.0000x reference)
//
#include <hip/hip_runtime.h>
#include <math.h>

// ---------------- graph build ----------------

__global__ void zero_i32(int* __restrict__ p, int n) {
  int i = blockIdx.x * 256 + threadIdx.x;
  if (i < n) p[i] = 0;
}

__global__ void hist_kernel(const int* __restrict__ dst, int* __restrict__ counts, int E) {
  int e = blockIdx.x * 256 + threadIdx.x;
  if (e < E) atomicAdd(&counts[dst[e]], 1);
}

// block scans a 1024-tile (256 thr x 4), writes per-element exclusive offsets + tile total
__global__ void scan1_kernel(const int* __restrict__ counts, int* __restrict__ offsets,
                             int* __restrict__ tileSums, int N) {
  __shared__ int sd[256];
  int t = threadIdx.x;
  int base = blockIdx.x * 1024 + t * 4;
  int v[4];
#pragma unroll
  for (int i = 0; i < 4; i++) v[i] = (base + i < N) ? counts[base + i] : 0;
  int s = v[0] + v[1] + v[2] + v[3];
  sd[t] = s;
  __syncthreads();
  int acc = s;
  for (int off = 1; off < 256; off <<= 1) {
    int add = (t >= off) ? sd[t - off] : 0;
    __syncthreads();
    acc += add;
    sd[t] = acc;
    __syncthreads();
  }
  int run = acc - s;  // exclusive prefix of this thread's 4-chunk
#pragma unroll
  for (int i = 0; i < 4; i++) {
    if (base + i < N) offsets[base + i] = run;
    run += v[i];
  }
  if (t == 255) tileSums[blockIdx.x] = acc;
}

// single block exclusive-scans tile sums (nT <= 128)
__global__ void scan2_kernel(int* __restrict__ tileSums, int nT) {
  __shared__ int sd[128];
  int t = threadIdx.x;
  int v = (t < nT) ? tileSums[t] : 0;
  sd[t] = v;
  __syncthreads();
  int acc = v;
  for (int off = 1; off < 128; off <<= 1) {
    int add = (t >= off) ? sd[t - off] : 0;
    __syncthreads();
    acc += add;
    sd[t] = acc;
    __syncthreads();
  }
  if (t < nT) tileSums[t] = acc - v;  // exclusive
}

__global__ void scan3_kernel(int* __restrict__ offsets, const int* __restrict__ tileSums,
                             int* __restrict__ cursor, int N) {
  int i = blockIdx.x * 256 + threadIdx.x;
  if (i >= N) return;
  int o = offsets[i] + tileSums[i >> 10];
  offsets[i] = o;
  cursor[i] = o;
}

__global__ void scatter_kernel(const int* __restrict__ src, const int* __restrict__ dst,
                               int* __restrict__ cursor, int* __restrict__ csr, int E) {
  int e = blockIdx.x * 256 + threadIdx.x;
  if (e >= E) return;
  int d = dst[e];
  int pos = atomicAdd(&cursor[d], 1);
  csr[pos] = src[e];
}

// ---------------- aggregation: segment max over incoming edges ----------------
// one wave64 per node; lane owns 2 dims (D=128)

template <int D>
__global__ void agg_max_kernel(const float* __restrict__ feat, const int* __restrict__ csr,
                               const int* __restrict__ offsets, const int* __restrict__ counts,
                               float* __restrict__ agg, int N) {
  int lane = threadIdx.x & 63;
  int w = (blockIdx.x * blockDim.x + threadIdx.x) >> 6;
  if (w >= N) return;
  int start = offsets[w];
  int deg = counts[w];
  float2 m = make_float2(0.0f, 0.0f);  // PyG scatter-max: 0 for isolated nodes
  if (deg > 0) {
    m = make_float2(-INFINITY, -INFINITY);
    for (int e = 0; e < deg; e++) {
      int s = csr[start + e];
      float2 v = *(const float2*)(feat + (size_t)s * D + lane * 2);
      m.x = fmaxf(m.x, v.x);
      m.y = fmaxf(m.y, v.y);
    }
  }
  *(float2*)(agg + (size_t)w * D + lane * 2) = m;
}

// ---------------- fused dual-GEMM + bias + L2 normalize (+ ReLU) ----------------
// out[n][c] = sum_k agg[n][k]*Wl[k][c] + x[n][k]*Wr[k][c] + b[c]; row-L2-normalize; opt relu
// D (input dim) = 128. Block: 256 thr, 64 nodes. thread t: tc=t&15 (col grp), tn=t>>4 (node grp of 4)

template <int DOUT, bool RELU>
__global__ __launch_bounds__(256) void sage_gemm_kernel(
    const float* __restrict__ A, const float* __restrict__ X, const float* __restrict__ Wl,
    const float* __restrict__ Wr, const float* __restrict__ bias, float* __restrict__ out, int N) {
  constexpr int D = 128, KC = 32, BN = 64;
  constexpr int CPT = DOUT / 16;  // cols per thread (8 or 4)
  __shared__ float sA[BN][KC + 1];
  __shared__ float sX[BN][KC + 1];
  __shared__ float sWl[KC][DOUT];
  __shared__ float sWr[KC][DOUT];

  int t = threadIdx.x;
  int tc = t & 15;
  int tn = t >> 4;
  int node0 = blockIdx.x * BN;

  float acc[4][CPT];
#pragma unroll
  for (int i = 0; i < 4; i++)
#pragma unroll
    for (int j = 0; j < CPT; j++) acc[i][j] = 0.0f;

  for (int k0 = 0; k0 < D; k0 += KC) {
    __syncthreads();
    // stage A,X chunks: 64 rows x 32 floats = 512 float4, 2 per thread
#pragma unroll
    for (int i = 0; i < 2; i++) {
      int idx = t + i * 256;
      int row = idx >> 3, q = idx & 7;
      int n = node0 + row;
      float4 va = make_float4(0.f, 0.f, 0.f, 0.f), vx = va;
      if (n < N) {
        va = *(const float4*)(A + (size_t)n * D + k0 + q * 4);
        vx = *(const float4*)(X + (size_t)n * D + k0 + q * 4);
      }
      sA[row][q * 4 + 0] = va.x; sA[row][q * 4 + 1] = va.y;
      sA[row][q * 4 + 2] = va.z; sA[row][q * 4 + 3] = va.w;
      sX[row][q * 4 + 0] = vx.x; sX[row][q * 4 + 1] = vx.y;
      sX[row][q * 4 + 2] = vx.z; sX[row][q * 4 + 3] = vx.w;
    }
    // stage W chunks: KC x DOUT floats each
    constexpr int NW = (KC * DOUT / 4) / 256;  // 4 (DOUT=128) or 2 (DOUT=64)
#pragma unroll
    for (int i = 0; i < NW; i++) {
      int idx = t + i * 256;
      int row = idx / (DOUT / 4), c4 = idx % (DOUT / 4);
      *(float4*)&sWl[row][c4 * 4] = *(const float4*)(Wl + (size_t)(k0 + row) * DOUT + c4 * 4);
      *(float4*)&sWr[row][c4 * 4] = *(const float4*)(Wr + (size_t)(k0 + row) * DOUT + c4 * 4);
    }
    __syncthreads();
#pragma unroll
    for (int kk = 0; kk < KC; kk++) {
      float av[4], xv[4];
#pragma unroll
      for (int i = 0; i < 4; i++) {
        av[i] = sA[tn * 4 + i][kk];
        xv[i] = sX[tn * 4 + i][kk];
      }
      float wl[CPT], wr[CPT];
#pragma unroll
      for (int j = 0; j < CPT; j++) {
        wl[j] = sWl[kk][tc * CPT + j];
        wr[j] = sWr[kk][tc * CPT + j];
      }
#pragma unroll
      for (int i = 0; i < 4; i++)
#pragma unroll
        for (int j = 0; j < CPT; j++) acc[i][j] += av[i] * wl[j] + xv[i] * wr[j];
    }
  }

  // bias
  float bb[CPT];
#pragma unroll
  for (int j = 0; j < CPT; j++) bb[j] = bias[tc * CPT + j];
#pragma unroll
  for (int i = 0; i < 4; i++)
#pragma unroll
    for (int j = 0; j < CPT; j++) acc[i][j] += bb[j];

  // row L2 norm: reduce across the 16 consecutive lanes sharing tn
#pragma unroll
  for (int i = 0; i < 4; i++) {
    float ss = 0.f;
#pragma unroll
    for (int j = 0; j < CPT; j++) ss += acc[i][j] * acc[i][j];
#pragma unroll
    for (int off = 1; off < 16; off <<= 1) ss += __shfl_xor(ss, off, 64);
    float nrm = fmaxf(sqrtf(ss), 1e-12f);
    float inv = 1.0f / nrm;
#pragma unroll
    for (int j = 0; j < CPT; j++) {
      float v = acc[i][j] * inv;
      if (RELU) v = fmaxf(v, 0.0f);
      acc[i][j] = v;
    }
  }

  // store
#pragma unroll
  for (int i = 0; i < 4; i++) {
    int n = node0 + tn * 4 + i;
    if (n < N) {
      float* op = out + (size_t)n * DOUT + tc * CPT;
#pragma unroll
      for (int j4 = 0; j4 < CPT; j4 += 4)
        *(float4*)(op + j4) =
            make_float4(acc[i][j4 + 0], acc[i][j4 + 1], acc[i][j4 + 2], acc[i][j4 + 3]);
    }
  }
}

// ---------------- launch ----------------

extern "C" void kernel_launch(void* const* d_in, const int* in_sizes, int n_in, void* d_out,
                              int out_size, void* d_ws, size_t ws_size, hipStream_t stream) {
  const float* x = (const float*)d_in[0];
  const int* ei = (const int*)d_in[1];
  const float* Wl1 = (const float*)d_in[2];
  const float* Wr1 = (const float*)d_in[3];
  const float* b1 = (const float*)d_in[4];
  const float* Wl2 = (const float*)d_in[5];
  const float* Wr2 = (const float*)d_in[6];
  const float* b2 = (const float*)d_in[7];
  float* out = (float*)d_out;

  const int E = in_sizes[1] / 2;
  const int N = in_sizes[0] / 128;
  const int D = 128;

  const int* src = ei;
  const int* dst = ei + E;

  // workspace carve-up (512B aligned)
  char* w = (char*)d_ws;
  size_t off = 0;
  auto alloc = [&](size_t bytes) {
    void* p = w + off;
    off = (off + bytes + 511) & ~((size_t)511);
    return p;
  };
  int* counts = (int*)alloc((size_t)N * 4);
  int* offsets = (int*)alloc((size_t)N * 4);
  int* cursor = (int*)alloc((size_t)N * 4);
  int* tileSums = (int*)alloc(512);
  int* csr = (int*)alloc((size_t)E * 4);
  float* agg = (float*)alloc((size_t)N * D * 4);
  float* h = (float*)alloc((size_t)N * D * 4);
  (void)ws_size;

  const int nTiles = (N + 1023) / 1024;  // 98

  zero_i32<<<(N + 255) / 256, 256, 0, stream>>>(counts, N);
  hist_kernel<<<(E + 255) / 256, 256, 0, stream>>>(dst, counts, E);
  scan1_kernel<<<nTiles, 256, 0, stream>>>(counts, offsets, tileSums, N);
  scan2_kernel<<<1, 128, 0, stream>>>(tileSums, nTiles);
  scan3_kernel<<<(N + 255) / 256, 256, 0, stream>>>(offsets, tileSums, cursor, N);
  scatter_kernel<<<(E + 255) / 256, 256, 0, stream>>>(src, dst, cursor, csr, E);

  // layer 1
  agg_max_kernel<128><<<(N * 64 + 255) / 256, 256, 0, stream>>>(x, csr, offsets, counts, agg, N);
  sage_gemm_kernel<128, true>
      <<<(N + 63) / 64, 256, 0, stream>>>(agg, x, Wl1, Wr1, b1, h, N);

  // layer 2
  agg_max_kernel<128><<<(N * 64 + 255) / 256, 256, 0, stream>>>(h, csr, offsets, counts, agg, N);
  sage_gemm_kernel<64, false>
      <<<(N + 63) / 64, 256, 0, stream>>>(agg, h, Wl2, Wr2, b2, out, N);
}

// Round 2
// 532.821 us; speedup vs baseline: 1.8272x; 1.8272x over previous
//
#include <hip/hip_runtime.h>
#include <math.h>

typedef __attribute__((ext_vector_type(8))) short short8;
typedef __attribute__((ext_vector_type(4))) float floatx4;

static __device__ __forceinline__ ushort f32_to_bf16_rne(float f) {
  union { float f; unsigned int i; } c;
  c.f = f;
  unsigned int lsb = (c.i >> 16) & 1u;
  c.i += 0x7fffu + lsb;
  return (ushort)(c.i >> 16);
}
static __device__ __forceinline__ float bf16_lo(unsigned int v) {
  union { unsigned int i; float f; } c;
  c.i = v << 16;
  return c.f;
}
static __device__ __forceinline__ float bf16_hi(unsigned int v) {
  union { unsigned int i; float f; } c;
  c.i = v & 0xffff0000u;
  return c.f;
}

// ---------------- graph build ----------------

__global__ void zero_i32(int* __restrict__ p, int n) {
  int i = blockIdx.x * 256 + threadIdx.x;
  if (i < n) p[i] = 0;
}

__global__ void hist_kernel(const int* __restrict__ dst, int* __restrict__ counts, int E) {
  int e = blockIdx.x * 256 + threadIdx.x;
  if (e < E) atomicAdd(&counts[dst[e]], 1);
}

__global__ void scan1_kernel(const int* __restrict__ counts, int* __restrict__ offsets,
                             int* __restrict__ tileSums, int N) {
  __shared__ int sd[256];
  int t = threadIdx.x;
  int base = blockIdx.x * 1024 + t * 4;
  int v[4];
#pragma unroll
  for (int i = 0; i < 4; i++) v[i] = (base + i < N) ? counts[base + i] : 0;
  int s = v[0] + v[1] + v[2] + v[3];
  sd[t] = s;
  __syncthreads();
  int acc = s;
  for (int off = 1; off < 256; off <<= 1) {
    int add = (t >= off) ? sd[t - off] : 0;
    __syncthreads();
    acc += add;
    sd[t] = acc;
    __syncthreads();
  }
  int run = acc - s;
#pragma unroll
  for (int i = 0; i < 4; i++) {
    if (base + i < N) offsets[base + i] = run;
    run += v[i];
  }
  if (t == 255) tileSums[blockIdx.x] = acc;
}

__global__ void scan2_kernel(int* __restrict__ tileSums, int nT) {
  __shared__ int sd[128];
  int t = threadIdx.x;
  int v = (t < nT) ? tileSums[t] : 0;
  sd[t] = v;
  __syncthreads();
  int acc = v;
  for (int off = 1; off < 128; off <<= 1) {
    int add = (t >= off) ? sd[t - off] : 0;
    __syncthreads();
    acc += add;
    sd[t] = acc;
    __syncthreads();
  }
  if (t < nT) tileSums[t] = acc - v;
}

__global__ void scan3_kernel(int* __restrict__ offsets, const int* __restrict__ tileSums,
                             int* __restrict__ cursor, int N) {
  int i = blockIdx.x * 256 + threadIdx.x;
  if (i >= N) return;
  int o = offsets[i] + tileSums[i >> 10];
  offsets[i] = o;
  cursor[i] = o;
}

__global__ void scatter_kernel(const int* __restrict__ src, const int* __restrict__ dst,
                               int* __restrict__ cursor, int* __restrict__ csr, int E) {
  int e = blockIdx.x * 256 + threadIdx.x;
  if (e >= E) return;
  int d = dst[e];
  int pos = atomicAdd(&cursor[d], 1);
  csr[pos] = src[e];
}

// ---------------- conversions ----------------

__global__ void f32_to_bf16_kernel(const float* __restrict__ in, ushort* __restrict__ out, int n) {
  int i = (blockIdx.x * 256 + threadIdx.x) * 8;
  if (i >= n) return;
  float4 a = *(const float4*)(in + i);
  float4 b = *(const float4*)(in + i + 4);
  union { ushort u[8]; short8 v; } r;
  r.u[0] = f32_to_bf16_rne(a.x); r.u[1] = f32_to_bf16_rne(a.y);
  r.u[2] = f32_to_bf16_rne(a.z); r.u[3] = f32_to_bf16_rne(a.w);
  r.u[4] = f32_to_bf16_rne(b.x); r.u[5] = f32_to_bf16_rne(b.y);
  r.u[6] = f32_to_bf16_rne(b.z); r.u[7] = f32_to_bf16_rne(b.w);
  *(short8*)(out + i) = r.v;
}

// WT[c][k] = bf16(W[k][c])
__global__ void wt_conv_kernel(const float* __restrict__ W, ushort* __restrict__ WT, int K, int C) {
  int idx = blockIdx.x * 256 + threadIdx.x;
  if (idx >= K * C) return;
  int k = idx / C, c = idx % C;
  WT[(size_t)c * K + k] = f32_to_bf16_rne(W[idx]);
}

// ---------------- aggregation: segment max (bf16 rows, 256B each) ----------------
// one wave per node; lane owns 2 bf16 dims packed in one u32

__global__ void agg_max_bf16_kernel(const ushort* __restrict__ feat, const int* __restrict__ csr,
                                    const int* __restrict__ offsets, const int* __restrict__ counts,
                                    unsigned int* __restrict__ aggb, int N) {
  int lane = threadIdx.x & 63;
  int node = (blockIdx.x * blockDim.x + threadIdx.x) >> 6;
  if (node >= N) return;
  const unsigned int* fu = (const unsigned int*)feat;
  int start = offsets[node];
  int deg = counts[node];
  float m0 = 0.0f, m1 = 0.0f;  // PyG scatter-max: 0 for isolated nodes
  if (deg > 0) {
    m0 = -INFINITY;
    m1 = -INFINITY;
    int e = 0;
    for (; e + 4 <= deg; e += 4) {
      int s0 = csr[start + e + 0];
      int s1 = csr[start + e + 1];
      int s2 = csr[start + e + 2];
      int s3 = csr[start + e + 3];
      unsigned int v0 = fu[(size_t)s0 * 64 + lane];
      unsigned int v1 = fu[(size_t)s1 * 64 + lane];
      unsigned int v2 = fu[(size_t)s2 * 64 + lane];
      unsigned int v3 = fu[(size_t)s3 * 64 + lane];
      m0 = fmaxf(m0, fmaxf(fmaxf(bf16_lo(v0), bf16_lo(v1)), fmaxf(bf16_lo(v2), bf16_lo(v3))));
      m1 = fmaxf(m1, fmaxf(fmaxf(bf16_hi(v0), bf16_hi(v1)), fmaxf(bf16_hi(v2), bf16_hi(v3))));
    }
    for (; e < deg; e++) {
      unsigned int v = fu[(size_t)csr[start + e] * 64 + lane];
      m0 = fmaxf(m0, bf16_lo(v));
      m1 = fmaxf(m1, bf16_hi(v));
    }
  }
  // m0/m1 are exact bf16 values (or 0) -> truncation is exact
  unsigned int res = (__float_as_uint(m0) >> 16) | (__float_as_uint(m1) & 0xffff0000u);
  aggb[(size_t)node * 64 + lane] = res;
}

// ---------------- fused dual-GEMM (MFMA bf16) + bias + L2 normalize (+ ReLU) ----------------
// out[n][c] = sum_k A[n][k]*Wl[k][c] + X[n][k]*Wr[k][c] + b[c]; L2-normalize rows; opt relu.
// Block: 256 thr = 4 waves, 128 nodes (wave handles 32 rows as 2x 16-row MFMA tiles).
// No LDS. A frags: lane&15 = row, lane>>4 = k-octet. B frags from transposed weights WT[c][k].

template <int DOUT, bool RELU, bool OUTBF16>
__global__ __launch_bounds__(256) void gemm_mfma_kernel(
    const ushort* __restrict__ A, const ushort* __restrict__ X, const ushort* __restrict__ WlT,
    const ushort* __restrict__ WrT, const float* __restrict__ bias, void* __restrict__ outp,
    int N) {
  constexpr int D = 128;
  constexpr int NCT = DOUT / 16;
  int t = threadIdx.x;
  int lane = t & 63;
  int wid = t >> 6;
  int l16 = lane & 15;
  int lk = lane >> 4;
  int rowbase = blockIdx.x * 128 + wid * 32;

  floatx4 acc[2][NCT];
#pragma unroll
  for (int rt = 0; rt < 2; rt++)
#pragma unroll
    for (int ct = 0; ct < NCT; ct++) acc[rt][ct] = (floatx4){0.f, 0.f, 0.f, 0.f};

  // clamp tail rows to a valid row (outputs for n>=N are never stored; rows are separable)
  int ra = rowbase + l16;       if (ra > N - 1) ra = N - 1;
  int rb = rowbase + 16 + l16;  if (rb > N - 1) rb = N - 1;
  const ushort* pA0 = A + (size_t)ra * D;
  const ushort* pA1 = A + (size_t)rb * D;
  const ushort* pX0 = X + (size_t)ra * D;
  const ushort* pX1 = X + (size_t)rb * D;

#pragma unroll
  for (int kc = 0; kc < 4; kc++) {
    int ko = kc * 32 + lk * 8;
    short8 a0 = *(const short8*)(pA0 + ko);
    short8 a1 = *(const short8*)(pA1 + ko);
    short8 x0 = *(const short8*)(pX0 + ko);
    short8 x1 = *(const short8*)(pX1 + ko);
#pragma unroll
    for (int ct = 0; ct < NCT; ct++) {
      int c = ct * 16 + l16;
      short8 bl = *(const short8*)(WlT + (size_t)c * D + ko);
      short8 br = *(const short8*)(WrT + (size_t)c * D + ko);
      acc[0][ct] = __builtin_amdgcn_mfma_f32_16x16x32_bf16(a0, bl, acc[0][ct], 0, 0, 0);
      acc[0][ct] = __builtin_amdgcn_mfma_f32_16x16x32_bf16(x0, br, acc[0][ct], 0, 0, 0);
      acc[1][ct] = __builtin_amdgcn_mfma_f32_16x16x32_bf16(a1, bl, acc[1][ct], 0, 0, 0);
      acc[1][ct] = __builtin_amdgcn_mfma_f32_16x16x32_bf16(x1, br, acc[1][ct], 0, 0, 0);
    }
  }

  // bias (C/D layout: col = ct*16 + l16, row = rt*16 + lk*4 + reg)
  float bb[NCT];
#pragma unroll
  for (int ct = 0; ct < NCT; ct++) bb[ct] = bias[ct * 16 + l16];
#pragma unroll
  for (int rt = 0; rt < 2; rt++)
#pragma unroll
    for (int ct = 0; ct < NCT; ct++)
#pragma unroll
      for (int r = 0; r < 4; r++) acc[rt][ct][r] += bb[ct];

#pragma unroll
  for (int rt = 0; rt < 2; rt++) {
#pragma unroll
    for (int r = 0; r < 4; r++) {
      float ss = 0.f;
#pragma unroll
      for (int ct = 0; ct < NCT; ct++) ss += acc[rt][ct][r] * acc[rt][ct][r];
      ss += __shfl_xor(ss, 1);
      ss += __shfl_xor(ss, 2);
      ss += __shfl_xor(ss, 4);
      ss += __shfl_xor(ss, 8);
      float inv = 1.0f / fmaxf(sqrtf(ss), 1e-12f);
      int n = rowbase + rt * 16 + lk * 4 + r;
      if (n < N) {
#pragma unroll
        for (int ct = 0; ct < NCT; ct++) {
          float v = acc[rt][ct][r] * inv;
          if (RELU) v = fmaxf(v, 0.f);
          size_t o = (size_t)n * DOUT + ct * 16 + l16;
          if (OUTBF16)
            ((ushort*)outp)[o] = f32_to_bf16_rne(v);
          else
            ((float*)outp)[o] = v;
        }
      }
    }
  }
}

// ---------------- launch ----------------

extern "C" void kernel_launch(void* const* d_in, const int* in_sizes, int n_in, void* d_out,
                              int out_size, void* d_ws, size_t ws_size, hipStream_t stream) {
  const float* x = (const float*)d_in[0];
  const int* ei = (const int*)d_in[1];
  const float* Wl1 = (const float*)d_in[2];
  const float* Wr1 = (const float*)d_in[3];
  const float* b1 = (const float*)d_in[4];
  const float* Wl2 = (const float*)d_in[5];
  const float* Wr2 = (const float*)d_in[6];
  const float* b2 = (const float*)d_in[7];
  float* out = (float*)d_out;

  const int E = in_sizes[1] / 2;
  const int N = in_sizes[0] / 128;
  const int D = 128;

  const int* src = ei;
  const int* dst = ei + E;

  char* w = (char*)d_ws;
  size_t off = 0;
  auto alloc = [&](size_t bytes) {
    void* p = w + off;
    off = (off + bytes + 511) & ~((size_t)511);
    return p;
  };
  int* counts = (int*)alloc((size_t)N * 4);
  int* offsets = (int*)alloc((size_t)N * 4);
  int* cursor = (int*)alloc((size_t)N * 4);
  int* tileSums = (int*)alloc(512);
  int* csr = (int*)alloc((size_t)E * 4);
  ushort* xb = (ushort*)alloc((size_t)N * D * 2);
  ushort* aggb = (ushort*)alloc((size_t)N * D * 2);
  ushort* hb = (ushort*)alloc((size_t)N * D * 2);
  ushort* WlT1 = (ushort*)alloc(128 * 128 * 2);
  ushort* WrT1 = (ushort*)alloc(128 * 128 * 2);
  ushort* WlT2 = (ushort*)alloc(128 * 64 * 2);
  ushort* WrT2 = (ushort*)alloc(128 * 64 * 2);
  (void)ws_size;

  const int nTiles = (N + 1023) / 1024;

  // graph build (reused by both layers)
  zero_i32<<<(N + 255) / 256, 256, 0, stream>>>(counts, N);
  hist_kernel<<<(E + 255) / 256, 256, 0, stream>>>(dst, counts, E);
  scan1_kernel<<<nTiles, 256, 0, stream>>>(counts, offsets, tileSums, N);
  scan2_kernel<<<1, 128, 0, stream>>>(tileSums, nTiles);
  scan3_kernel<<<(N + 255) / 256, 256, 0, stream>>>(offsets, tileSums, cursor, N);
  scatter_kernel<<<(E + 255) / 256, 256, 0, stream>>>(src, dst, cursor, csr, E);

  // conversions
  f32_to_bf16_kernel<<<(N * D / 8 + 255) / 256, 256, 0, stream>>>(x, xb, N * D);
  wt_conv_kernel<<<(128 * 128 + 255) / 256, 256, 0, stream>>>(Wl1, WlT1, 128, 128);
  wt_conv_kernel<<<(128 * 128 + 255) / 256, 256, 0, stream>>>(Wr1, WrT1, 128, 128);
  wt_conv_kernel<<<(128 * 64 + 255) / 256, 256, 0, stream>>>(Wl2, WlT2, 128, 64);
  wt_conv_kernel<<<(128 * 64 + 255) / 256, 256, 0, stream>>>(Wr2, WrT2, 128, 64);

  const int nbGemm = (N + 127) / 128;

  // layer 1
  agg_max_bf16_kernel<<<(N * 64 + 255) / 256, 256, 0, stream>>>(xb, csr, offsets, counts,
                                                                (unsigned int*)aggb, N);
  gemm_mfma_kernel<128, true, true>
      <<<nbGemm, 256, 0, stream>>>(aggb, xb, WlT1, WrT1, b1, hb, N);

  // layer 2
  agg_max_bf16_kernel<<<(N * 64 + 255) / 256, 256, 0, stream>>>(hb, csr, offsets, counts,
                                                                (unsigned int*)aggb, N);
  gemm_mfma_kernel<64, false, false>
      <<<nbGemm, 256, 0, stream>>>(aggb, hb, WlT2, WrT2, b2, out, N);
}

// Round 3
// 396.711 us; speedup vs baseline: 2.4541x; 1.3431x over previous
//
#include <hip/hip_runtime.h>
#include <math.h>

typedef __attribute__((ext_vector_type(8))) short short8;
typedef __attribute__((ext_vector_type(4))) float floatx4;

static __device__ __forceinline__ ushort f32_to_bf16_rne(float f) {
  union { float f; unsigned int i; } c;
  c.f = f;
  unsigned int lsb = (c.i >> 16) & 1u;
  c.i += 0x7fffu + lsb;
  return (ushort)(c.i >> 16);
}
static __device__ __forceinline__ float bf16_lo(unsigned int v) {
  union { unsigned int i; float f; } c;
  c.i = v << 16;
  return c.f;
}
static __device__ __forceinline__ float bf16_hi(unsigned int v) {
  union { unsigned int i; float f; } c;
  c.i = v & 0xffff0000u;
  return c.f;
}

// ---------------- graph build: 2-level locality-staged CSR ----------------
// bucket = dst >> 9 (512 nodes per bucket). NBLK chunks of edges.

#define NBLK 256

// Pass A: per-chunk LDS histogram over buckets -> bh[bucket*NBLK + blk]
__global__ __launch_bounds__(256) void binhist_kernel(const int* __restrict__ dst,
                                                      int* __restrict__ bh, int E, int EBLK,
                                                      int NBUCKET) {
  __shared__ int h[256];
  int t = threadIdx.x, blk = blockIdx.x;
  h[t] = 0;
  __syncthreads();
  int e0 = blk * EBLK, e1 = min(E, e0 + EBLK);
  for (int e = e0 + t; e < e1; e += 256) atomicAdd(&h[dst[e] >> 9], 1);
  __syncthreads();
  if (t < NBUCKET) bh[t * NBLK + blk] = h[t];
}

// generic scans (used for the flat (bucket,block) offset table)
__global__ void scan1_kernel(const int* __restrict__ counts, int* __restrict__ offsets,
                             int* __restrict__ tileSums, int N) {
  __shared__ int sd[256];
  int t = threadIdx.x;
  int base = blockIdx.x * 1024 + t * 4;
  int v[4];
#pragma unroll
  for (int i = 0; i < 4; i++) v[i] = (base + i < N) ? counts[base + i] : 0;
  int s = v[0] + v[1] + v[2] + v[3];
  sd[t] = s;
  __syncthreads();
  int acc = s;
  for (int off = 1; off < 256; off <<= 1) {
    int add = (t >= off) ? sd[t - off] : 0;
    __syncthreads();
    acc += add;
    sd[t] = acc;
    __syncthreads();
  }
  int run = acc - s;
#pragma unroll
  for (int i = 0; i < 4; i++) {
    if (base + i < N) offsets[base + i] = run;
    run += v[i];
  }
  if (t == 255) tileSums[blockIdx.x] = acc;
}

__global__ void scan2_kernel(int* __restrict__ tileSums, int nT) {
  __shared__ int sd[128];
  int t = threadIdx.x;
  int v = (t < nT) ? tileSums[t] : 0;
  sd[t] = v;
  __syncthreads();
  int acc = v;
  for (int off = 1; off < 128; off <<= 1) {
    int add = (t >= off) ? sd[t - off] : 0;
    __syncthreads();
    acc += add;
    sd[t] = acc;
    __syncthreads();
  }
  if (t < nT) tileSums[t] = acc - v;
}

__global__ void scan3_nc_kernel(int* __restrict__ offsets, const int* __restrict__ tileSums,
                                int N) {
  int i = blockIdx.x * 256 + threadIdx.x;
  if (i >= N) return;
  offsets[i] += tileSums[i >> 10];
}

// Pass C: scatter (src,dst) records grouped by bucket, LDS cursors
__global__ __launch_bounds__(256) void binscatter_kernel(const int* __restrict__ src,
                                                         const int* __restrict__ dst,
                                                         const int* __restrict__ bhOff,
                                                         int2* __restrict__ binned, int E,
                                                         int EBLK, int NBUCKET) {
  __shared__ int cur[256];
  int t = threadIdx.x, blk = blockIdx.x;
  if (t < NBUCKET) cur[t] = bhOff[t * NBLK + blk];
  __syncthreads();
  int e0 = blk * EBLK, e1 = min(E, e0 + EBLK);
  for (int e = e0 + t; e < e1; e += 256) {
    int d = dst[e];
    int pos = atomicAdd(&cur[d >> 9], 1);
    binned[pos] = make_int2(src[e], d);
  }
}

// Pass D: one block per bucket. LDS node hist -> LDS scan -> counts/offsets -> LDS-cursor scatter.
__global__ __launch_bounds__(256) void bucket_build_kernel(
    const int2* __restrict__ binned, const int* __restrict__ bhOff, int* __restrict__ counts,
    int* __restrict__ offsets, int* __restrict__ csr, int N, int E, int NBUCKET) {
  __shared__ int h[512];
  __shared__ int lofs[512];
  __shared__ int cur[512];
  __shared__ int sd[256];
  int b = blockIdx.x, t = threadIdx.x;
  int S = bhOff[b * NBLK];
  int Send = (b + 1 < NBUCKET) ? bhOff[(b + 1) * NBLK] : E;
  h[t] = 0;
  h[t + 256] = 0;
  __syncthreads();
  for (int e = S + t; e < Send; e += 256) atomicAdd(&h[binned[e].y & 511], 1);
  __syncthreads();
  // exclusive scan of 512 counters with 256 threads (2 per thread)
  int h0 = h[2 * t], h1 = h[2 * t + 1];
  int s = h0 + h1;
  sd[t] = s;
  __syncthreads();
  int acc = s;
  for (int off = 1; off < 256; off <<= 1) {
    int add = (t >= off) ? sd[t - off] : 0;
    __syncthreads();
    acc += add;
    sd[t] = acc;
    __syncthreads();
  }
  int run = acc - s;
  lofs[2 * t] = run;
  lofs[2 * t + 1] = run + h0;
  __syncthreads();
  int node0 = b * 512;
#pragma unroll
  for (int i = 0; i < 2; i++) {
    int l = t + i * 256;
    int node = node0 + l;
    if (node < N) {
      counts[node] = h[l];
      offsets[node] = S + lofs[l];
    }
    cur[l] = S + lofs[l];
  }
  __syncthreads();
  for (int e = S + t; e < Send; e += 256) {
    int2 r = binned[e];
    int pos = atomicAdd(&cur[r.y & 511], 1);
    csr[pos] = r.x;
  }
}

// ---------------- conversions ----------------

__global__ void f32_to_bf16_kernel(const float* __restrict__ in, ushort* __restrict__ out, int n) {
  int i = (blockIdx.x * 256 + threadIdx.x) * 8;
  if (i >= n) return;
  float4 a = *(const float4*)(in + i);
  float4 b = *(const float4*)(in + i + 4);
  union { ushort u[8]; short8 v; } r;
  r.u[0] = f32_to_bf16_rne(a.x); r.u[1] = f32_to_bf16_rne(a.y);
  r.u[2] = f32_to_bf16_rne(a.z); r.u[3] = f32_to_bf16_rne(a.w);
  r.u[4] = f32_to_bf16_rne(b.x); r.u[5] = f32_to_bf16_rne(b.y);
  r.u[6] = f32_to_bf16_rne(b.z); r.u[7] = f32_to_bf16_rne(b.w);
  *(short8*)(out + i) = r.v;
}

// WT[c][k] = bf16(W[k][c])
__global__ void wt_conv_kernel(const float* __restrict__ W, ushort* __restrict__ WT, int K, int C) {
  int idx = blockIdx.x * 256 + threadIdx.x;
  if (idx >= K * C) return;
  int k = idx / C, c = idx % C;
  WT[(size_t)c * K + k] = f32_to_bf16_rne(W[idx]);
}

// ---------------- aggregation: segment max (bf16 rows, 256B each) ----------------

__global__ void agg_max_bf16_kernel(const ushort* __restrict__ feat, const int* __restrict__ csr,
                                    const int* __restrict__ offsets, const int* __restrict__ counts,
                                    unsigned int* __restrict__ aggb, int N) {
  int lane = threadIdx.x & 63;
  int node = (blockIdx.x * blockDim.x + threadIdx.x) >> 6;
  if (node >= N) return;
  const unsigned int* fu = (const unsigned int*)feat;
  int start = offsets[node];
  int deg = counts[node];
  float m0 = 0.0f, m1 = 0.0f;  // PyG scatter-max: 0 for isolated nodes
  if (deg > 0) {
    m0 = -INFINITY;
    m1 = -INFINITY;
    int e = 0;
    for (; e + 4 <= deg; e += 4) {
      int s0 = csr[start + e + 0];
      int s1 = csr[start + e + 1];
      int s2 = csr[start + e + 2];
      int s3 = csr[start + e + 3];
      unsigned int v0 = fu[(size_t)s0 * 64 + lane];
      unsigned int v1 = fu[(size_t)s1 * 64 + lane];
      unsigned int v2 = fu[(size_t)s2 * 64 + lane];
      unsigned int v3 = fu[(size_t)s3 * 64 + lane];
      m0 = fmaxf(m0, fmaxf(fmaxf(bf16_lo(v0), bf16_lo(v1)), fmaxf(bf16_lo(v2), bf16_lo(v3))));
      m1 = fmaxf(m1, fmaxf(fmaxf(bf16_hi(v0), bf16_hi(v1)), fmaxf(bf16_hi(v2), bf16_hi(v3))));
    }
    for (; e < deg; e++) {
      unsigned int v = fu[(size_t)csr[start + e] * 64 + lane];
      m0 = fmaxf(m0, bf16_lo(v));
      m1 = fmaxf(m1, bf16_hi(v));
    }
  }
  unsigned int res = (__float_as_uint(m0) >> 16) | (__float_as_uint(m1) & 0xffff0000u);
  aggb[(size_t)node * 64 + lane] = res;
}

// ---------------- fused dual-GEMM (MFMA bf16) + bias + L2 normalize (+ ReLU) ----------------

template <int DOUT, bool RELU, bool OUTBF16>
__global__ __launch_bounds__(256) void gemm_mfma_kernel(
    const ushort* __restrict__ A, const ushort* __restrict__ X, const ushort* __restrict__ WlT,
    const ushort* __restrict__ WrT, const float* __restrict__ bias, void* __restrict__ outp,
    int N) {
  constexpr int D = 128;
  constexpr int NCT = DOUT / 16;
  int t = threadIdx.x;
  int lane = t & 63;
  int wid = t >> 6;
  int l16 = lane & 15;
  int lk = lane >> 4;
  int rowbase = blockIdx.x * 128 + wid * 32;

  floatx4 acc[2][NCT];
#pragma unroll
  for (int rt = 0; rt < 2; rt++)
#pragma unroll
    for (int ct = 0; ct < NCT; ct++) acc[rt][ct] = (floatx4){0.f, 0.f, 0.f, 0.f};

  int ra = rowbase + l16;       if (ra > N - 1) ra = N - 1;
  int rb = rowbase + 16 + l16;  if (rb > N - 1) rb = N - 1;
  const ushort* pA0 = A + (size_t)ra * D;
  const ushort* pA1 = A + (size_t)rb * D;
  const ushort* pX0 = X + (size_t)ra * D;
  const ushort* pX1 = X + (size_t)rb * D;

#pragma unroll
  for (int kc = 0; kc < 4; kc++) {
    int ko = kc * 32 + lk * 8;
    short8 a0 = *(const short8*)(pA0 + ko);
    short8 a1 = *(const short8*)(pA1 + ko);
    short8 x0 = *(const short8*)(pX0 + ko);
    short8 x1 = *(const short8*)(pX1 + ko);
#pragma unroll
    for (int ct = 0; ct < NCT; ct++) {
      int c = ct * 16 + l16;
      short8 bl = *(const short8*)(WlT + (size_t)c * D + ko);
      short8 br = *(const short8*)(WrT + (size_t)c * D + ko);
      acc[0][ct] = __builtin_amdgcn_mfma_f32_16x16x32_bf16(a0, bl, acc[0][ct], 0, 0, 0);
      acc[0][ct] = __builtin_amdgcn_mfma_f32_16x16x32_bf16(x0, br, acc[0][ct], 0, 0, 0);
      acc[1][ct] = __builtin_amdgcn_mfma_f32_16x16x32_bf16(a1, bl, acc[1][ct], 0, 0, 0);
      acc[1][ct] = __builtin_amdgcn_mfma_f32_16x16x32_bf16(x1, br, acc[1][ct], 0, 0, 0);
    }
  }

  float bb[NCT];
#pragma unroll
  for (int ct = 0; ct < NCT; ct++) bb[ct] = bias[ct * 16 + l16];
#pragma unroll
  for (int rt = 0; rt < 2; rt++)
#pragma unroll
    for (int ct = 0; ct < NCT; ct++)
#pragma unroll
      for (int r = 0; r < 4; r++) acc[rt][ct][r] += bb[ct];

#pragma unroll
  for (int rt = 0; rt < 2; rt++) {
#pragma unroll
    for (int r = 0; r < 4; r++) {
      float ss = 0.f;
#pragma unroll
      for (int ct = 0; ct < NCT; ct++) ss += acc[rt][ct][r] * acc[rt][ct][r];
      ss += __shfl_xor(ss, 1);
      ss += __shfl_xor(ss, 2);
      ss += __shfl_xor(ss, 4);
      ss += __shfl_xor(ss, 8);
      float inv = 1.0f / fmaxf(sqrtf(ss), 1e-12f);
      int n = rowbase + rt * 16 + lk * 4 + r;
      if (n < N) {
#pragma unroll
        for (int ct = 0; ct < NCT; ct++) {
          float v = acc[rt][ct][r] * inv;
          if (RELU) v = fmaxf(v, 0.f);
          size_t o = (size_t)n * DOUT + ct * 16 + l16;
          if (OUTBF16)
            ((ushort*)outp)[o] = f32_to_bf16_rne(v);
          else
            ((float*)outp)[o] = v;
        }
      }
    }
  }
}

// ---------------- launch ----------------

extern "C" void kernel_launch(void* const* d_in, const int* in_sizes, int n_in, void* d_out,
                              int out_size, void* d_ws, size_t ws_size, hipStream_t stream) {
  const float* x = (const float*)d_in[0];
  const int* ei = (const int*)d_in[1];
  const float* Wl1 = (const float*)d_in[2];
  const float* Wr1 = (const float*)d_in[3];
  const float* b1 = (const float*)d_in[4];
  const float* Wl2 = (const float*)d_in[5];
  const float* Wr2 = (const float*)d_in[6];
  const float* b2 = (const float*)d_in[7];
  float* out = (float*)d_out;

  const int E = in_sizes[1] / 2;
  const int N = in_sizes[0] / 128;
  const int D = 128;

  const int* src = ei;
  const int* dst = ei + E;

  char* w = (char*)d_ws;
  size_t off = 0;
  auto alloc = [&](size_t bytes) {
    void* p = w + off;
    off = (off + bytes + 511) & ~((size_t)511);
    return p;
  };
  const int NBUCKET = (N + 511) >> 9;        // 196
  const int M = NBUCKET * NBLK;              // flat (bucket,block) table size
  int* bh = (int*)alloc((size_t)M * 4);
  int* tileSums = (int*)alloc(512);
  int* counts = (int*)alloc((size_t)N * 4);
  int* offsets = (int*)alloc((size_t)N * 4);
  int2* binned = (int2*)alloc((size_t)E * 8);
  int* csr = (int*)alloc((size_t)E * 4);
  ushort* xb = (ushort*)alloc((size_t)N * D * 2);
  ushort* aggb = (ushort*)alloc((size_t)N * D * 2);
  ushort* hb = (ushort*)alloc((size_t)N * D * 2);
  ushort* WlT1 = (ushort*)alloc(128 * 128 * 2);
  ushort* WrT1 = (ushort*)alloc(128 * 128 * 2);
  ushort* WlT2 = (ushort*)alloc(128 * 64 * 2);
  ushort* WrT2 = (ushort*)alloc(128 * 64 * 2);
  (void)ws_size;

  const int EBLK = (E + NBLK - 1) / NBLK;
  const int nTiles = (M + 1023) / 1024;  // 49

  // graph build (reused by both layers)
  binhist_kernel<<<NBLK, 256, 0, stream>>>(dst, bh, E, EBLK, NBUCKET);
  scan1_kernel<<<nTiles, 256, 0, stream>>>(bh, bh, tileSums, M);  // in-place ok (tile-local)
  scan2_kernel<<<1, 128, 0, stream>>>(tileSums, nTiles);
  scan3_nc_kernel<<<(M + 255) / 256, 256, 0, stream>>>(bh, tileSums, M);
  binscatter_kernel<<<NBLK, 256, 0, stream>>>(src, dst, bh, binned, E, EBLK, NBUCKET);
  bucket_build_kernel<<<NBUCKET, 256, 0, stream>>>(binned, bh, counts, offsets, csr, N, E,
                                                   NBUCKET);

  // conversions
  f32_to_bf16_kernel<<<(N * D / 8 + 255) / 256, 256, 0, stream>>>(x, xb, N * D);
  wt_conv_kernel<<<(128 * 128 + 255) / 256, 256, 0, stream>>>(Wl1, WlT1, 128, 128);
  wt_conv_kernel<<<(128 * 128 + 255) / 256, 256, 0, stream>>>(Wr1, WrT1, 128, 128);
  wt_conv_kernel<<<(128 * 64 + 255) / 256, 256, 0, stream>>>(Wl2, WlT2, 128, 64);
  wt_conv_kernel<<<(128 * 64 + 255) / 256, 256, 0, stream>>>(Wr2, WrT2, 128, 64);

  const int nbGemm = (N + 127) / 128;

  // layer 1
  agg_max_bf16_kernel<<<(N * 64 + 255) / 256, 256, 0, stream>>>(xb, csr, offsets, counts,
                                                                (unsigned int*)aggb, N);
  gemm_mfma_kernel<128, true, true>
      <<<nbGemm, 256, 0, stream>>>(aggb, xb, WlT1, WrT1, b1, hb, N);

  // layer 2
  agg_max_bf16_kernel<<<(N * 64 + 255) / 256, 256, 0, stream>>>(hb, csr, offsets, counts,
                                                                (unsigned int*)aggb, N);
  gemm_mfma_kernel<64, false, false>
      <<<nbGemm, 256, 0, stream>>>(aggb, hb, WlT2, WrT2, b2, out, N);
}